// Round 1
// baseline (243.264 us; speedup 1.0000x reference)
//
#include <hip/hip_runtime.h>

// ReorderObjectsLayer: per-event stable stream-compaction of 4 particle groups.
// Input/Output: (N, 16, 3) float32. Groups: jets [0,6), electrons [6,9),
// muons [9,12), photons [12,15), met row 15 pass-through.
// Semantics (== jnp reference): within each group, rows with col0 > 0 are
// moved to the front (stable), remaining slots zeroed.

template<int B, int S>
__device__ __forceinline__ void compact_group(const float* in, float* o) {
    // Build keep-mask for this group (S <= 6 bits).
    unsigned m = 0u;
#pragma unroll
    for (int s = 0; s < S; ++s)
        if (in[(B + s) * 3] > 0.0f) m |= (1u << s);

    // Branch-free rank-select: output slot j gets source row s iff
    // mask[s] set and popcount(mask below s) == j. All indices are
    // compile-time constants -> stays in registers (no scratch).
#pragma unroll
    for (int j = 0; j < S; ++j) {
        float a = 0.0f, b = 0.0f, c = 0.0f;
#pragma unroll
        for (int s = j; s < S; ++s) {   // j-th kept row can't be before index j
            bool take = (((m >> s) & 1u) != 0u) &&
                        (__popc(m & ((1u << s) - 1u)) == j);
            a = take ? in[(B + s) * 3 + 0] : a;
            b = take ? in[(B + s) * 3 + 1] : b;
            c = take ? in[(B + s) * 3 + 2] : c;
        }
        o[(B + j) * 3 + 0] = a;
        o[(B + j) * 3 + 1] = b;
        o[(B + j) * 3 + 2] = c;
    }
}

__global__ __launch_bounds__(256)
void reorder_objects_kernel(const float* __restrict__ x,
                            float* __restrict__ out, int n) {
    int tid    = blockIdx.x * blockDim.x + threadIdx.x;
    int stride = gridDim.x * blockDim.x;
    for (int i = tid; i < n; i += stride) {
        const float4* __restrict__ xin =
            reinterpret_cast<const float4*>(x + (size_t)i * 48);
        float4 vin[12];
#pragma unroll
        for (int k = 0; k < 12; ++k) vin[k] = xin[k];
        const float* in = reinterpret_cast<const float*>(vin);

        float4 vout[12];
        float* o = reinterpret_cast<float*>(vout);

        compact_group<0, 6>(in, o);   // jets
        compact_group<6, 3>(in, o);   // electrons
        compact_group<9, 3>(in, o);   // muons
        compact_group<12, 3>(in, o);  // photons
        // met row 15: pass-through
        o[45] = in[45];
        o[46] = in[46];
        o[47] = in[47];

        float4* __restrict__ dst =
            reinterpret_cast<float4*>(out + (size_t)i * 48);
#pragma unroll
        for (int k = 0; k < 12; ++k) dst[k] = vout[k];
    }
}

extern "C" void kernel_launch(void* const* d_in, const int* in_sizes, int n_in,
                              void* d_out, int out_size, void* d_ws, size_t ws_size,
                              hipStream_t stream) {
    const float* x = (const float*)d_in[0];
    float* out = (float*)d_out;
    int n = in_sizes[0] / 48;   // events

    const int block = 256;
    int grid = (n + block - 1) / block;
    if (grid > 2048) grid = 2048;   // 2048 blk * 4 waves = 8192 waves = full chip
    reorder_objects_kernel<<<grid, block, 0, stream>>>(x, out, n);
}

// Round 2
// 162.657 us; speedup vs baseline: 1.4956x; 1.4956x over previous
//
#include <hip/hip_runtime.h>

// ReorderObjectsLayer: per-event stable stream-compaction of 4 particle groups.
// Input/Output: (N, 16, 3) float32. Groups: jets [0,6), electrons [6,9),
// muons [9,12), photons [12,15), met row 15 pass-through.
//
// Strategy: LDS-staged, fully coalesced global access.
//   stage 1: 256 threads load 256 events (48 KB) with lane-consecutive float4s
//   stage 2: thread t compacts event t entirely in registers (rank-select)
//   stage 3: lane-consecutive float4 stores from LDS
// LDS event stride = 52 dwords (48 payload + 4 pad, 16B aligned): 52*l mod 32
// walks all eight 4-bank groups every 8 lanes -> conflict-free ds_read_b128.

#define EPB 256          // events per block
#define F4E 12           // float4s per event
#define STRIDE_DW 52     // LDS dwords per event (48 + 4 pad)

template<int B, int S>
__device__ __forceinline__ void compact_group(const float* in, float* o) {
    unsigned m = 0u;
#pragma unroll
    for (int s = 0; s < S; ++s)
        if (in[(B + s) * 3] > 0.0f) m |= (1u << s);
#pragma unroll
    for (int j = 0; j < S; ++j) {
        float a = 0.0f, b = 0.0f, c = 0.0f;
#pragma unroll
        for (int s = j; s < S; ++s) {   // j-th kept row can't be before index j
            bool take = (((m >> s) & 1u) != 0u) &&
                        (__popc(m & ((1u << s) - 1u)) == j);
            a = take ? in[(B + s) * 3 + 0] : a;
            b = take ? in[(B + s) * 3 + 1] : b;
            c = take ? in[(B + s) * 3 + 2] : c;
        }
        o[(B + j) * 3 + 0] = a;
        o[(B + j) * 3 + 1] = b;
        o[(B + j) * 3 + 2] = c;
    }
}

__global__ __launch_bounds__(256)
void reorder_objects_kernel(const float* __restrict__ x,
                            float* __restrict__ out, int n) {
    __shared__ float lds[EPB * STRIDE_DW];   // 53248 B

    const int t = threadIdx.x;
    const size_t ev0 = (size_t)blockIdx.x * EPB;
    int validEvents = n - (int)ev0;
    if (validEvents > EPB) validEvents = EPB;
    const int validF4 = validEvents * F4E;

    // ---- stage 1: coalesced global -> LDS ----
    const float4* __restrict__ gin =
        reinterpret_cast<const float4*>(x + ev0 * 48);
#pragma unroll
    for (int k = 0; k < F4E; ++k) {
        int j = t + k * EPB;
        if (j < validF4) {
            float4 v = gin[j];
            int e = j / F4E;
            int r = j - e * F4E;
            *reinterpret_cast<float4*>(&lds[e * STRIDE_DW + r * 4]) = v;
        }
    }
    __syncthreads();

    // ---- stage 2: per-thread compaction in registers ----
    if (t < validEvents) {
        float* base = &lds[t * STRIDE_DW];
        float4 vin[F4E];
#pragma unroll
        for (int k = 0; k < F4E; ++k)
            vin[k] = reinterpret_cast<const float4*>(base)[k];
        const float* in = reinterpret_cast<const float*>(vin);

        float4 vout[F4E];
        float* o = reinterpret_cast<float*>(vout);

        compact_group<0, 6>(in, o);   // jets
        compact_group<6, 3>(in, o);   // electrons
        compact_group<9, 3>(in, o);   // muons
        compact_group<12, 3>(in, o);  // photons
        o[45] = in[45];               // met pass-through
        o[46] = in[46];
        o[47] = in[47];

#pragma unroll
        for (int k = 0; k < F4E; ++k)
            reinterpret_cast<float4*>(base)[k] = vout[k];
    }
    __syncthreads();

    // ---- stage 3: coalesced LDS -> global ----
    float4* __restrict__ gout = reinterpret_cast<float4*>(out + ev0 * 48);
#pragma unroll
    for (int k = 0; k < F4E; ++k) {
        int j = t + k * EPB;
        if (j < validF4) {
            int e = j / F4E;
            int r = j - e * F4E;
            gout[j] = *reinterpret_cast<const float4*>(&lds[e * STRIDE_DW + r * 4]);
        }
    }
}

extern "C" void kernel_launch(void* const* d_in, const int* in_sizes, int n_in,
                              void* d_out, int out_size, void* d_ws, size_t ws_size,
                              hipStream_t stream) {
    const float* x = (const float*)d_in[0];
    float* out = (float*)d_out;
    int n = in_sizes[0] / 48;   // events

    int grid = (n + EPB - 1) / EPB;   // exact grid, no grid-stride imbalance
    reorder_objects_kernel<<<grid, 256, 0, stream>>>(x, out, n);
}

// Round 3
// 131.993 us; speedup vs baseline: 1.8430x; 1.2323x over previous
//
#include <hip/hip_runtime.h>

// ReorderObjectsLayer: per-event stable stream-compaction of 4 particle groups.
// Input/Output: (N, 16, 3) float32. Groups: jets [0,6), electrons [6,9),
// muons [9,12), photons [12,15), met row 15 pass-through.
//
// LDS-staged, fully coalesced global access; nontemporal (streamed once).
//   stage 1: 256 threads load 128 events (26.6 KB) with lane-consecutive 16B loads
//   stage 2: event e split across two threads: t=e does jets (rows 0-5),
//            t=e+128 does electrons/muons/photons/met (rows 6-15).
//            Wave-uniform split (waves 0-1 vs 2-3), disjoint dword ranges.
//   stage 3: lane-consecutive 16B stores
// LDS event stride = 52 dwords (48 + 4 pad, 16B aligned): start bank (52*l)%32
// cycles all eight 4-bank groups every 8 lanes -> conflict-free b128 access.
// EPB=128 -> 26624 B LDS -> 6 blocks/CU = 24 waves/CU (vs 12 at EPB=256).

#define EPB 128          // events per block
#define F4E 12           // 16B chunks per event
#define STRIDE_DW 52     // LDS dwords per event (48 + 4 pad)
#define ITERS ((EPB * F4E) / 256)

typedef float f32x4 __attribute__((ext_vector_type(4)));

template<int S>
__device__ __forceinline__ void compact_rows(const float* in, float* o) {
    // in/o: S contiguous rows of 3 floats. Stable-compact rows with col0>0.
    unsigned m = 0u;
#pragma unroll
    for (int s = 0; s < S; ++s)
        if (in[s * 3] > 0.0f) m |= (1u << s);
#pragma unroll
    for (int j = 0; j < S; ++j) {
        float a = 0.0f, b = 0.0f, c = 0.0f;
#pragma unroll
        for (int s = j; s < S; ++s) {   // j-th kept row can't be before index j
            bool take = (((m >> s) & 1u) != 0u) &&
                        (__popc(m & ((1u << s) - 1u)) == j);
            a = take ? in[s * 3 + 0] : a;
            b = take ? in[s * 3 + 1] : b;
            c = take ? in[s * 3 + 2] : c;
        }
        o[j * 3 + 0] = a;
        o[j * 3 + 1] = b;
        o[j * 3 + 2] = c;
    }
}

__global__ __launch_bounds__(256)
void reorder_objects_kernel(const float* __restrict__ x,
                            float* __restrict__ out, int n) {
    __shared__ float lds[EPB * STRIDE_DW];   // 26624 B

    const int t = threadIdx.x;
    const size_t ev0 = (size_t)blockIdx.x * EPB;
    int validEvents = n - (int)ev0;
    if (validEvents > EPB) validEvents = EPB;
    const int validF4 = validEvents * F4E;

    // ---- stage 1: coalesced nontemporal global -> LDS ----
    const f32x4* __restrict__ gin =
        reinterpret_cast<const f32x4*>(x + ev0 * 48);
#pragma unroll
    for (int k = 0; k < ITERS; ++k) {
        int j = t + k * 256;
        if (j < validF4) {
            f32x4 v = __builtin_nontemporal_load(&gin[j]);
            int e = j / F4E;
            int r = j - e * F4E;
            *reinterpret_cast<f32x4*>(&lds[e * STRIDE_DW + r * 4]) = v;
        }
    }
    __syncthreads();

    // ---- stage 2: per-thread compaction (event split across 2 threads) ----
    if (t < EPB) {
        if (t < validEvents) {
            float* base = &lds[t * STRIDE_DW];       // jets: dwords 0..17
            float in[18], o[18];
#pragma unroll
            for (int i = 0; i < 18; ++i) in[i] = base[i];
            compact_rows<6>(in, o);
#pragma unroll
            for (int i = 0; i < 18; ++i) base[i] = o[i];
        }
    } else {
        int e = t - EPB;
        if (e < validEvents) {
            float* base = &lds[e * STRIDE_DW + 18];  // rows 6..15: dwords 18..47
            float in[30], o[30];
#pragma unroll
            for (int i = 0; i < 30; ++i) in[i] = base[i];
            compact_rows<3>(in + 0,  o + 0);   // electrons
            compact_rows<3>(in + 9,  o + 9);   // muons
            compact_rows<3>(in + 18, o + 18);  // photons
            o[27] = in[27];                    // met pass-through
            o[28] = in[28];
            o[29] = in[29];
#pragma unroll
            for (int i = 0; i < 30; ++i) base[i] = o[i];
        }
    }
    __syncthreads();

    // ---- stage 3: coalesced LDS -> nontemporal global ----
    f32x4* __restrict__ gout = reinterpret_cast<f32x4*>(out + ev0 * 48);
#pragma unroll
    for (int k = 0; k < ITERS; ++k) {
        int j = t + k * 256;
        if (j < validF4) {
            int e = j / F4E;
            int r = j - e * F4E;
            f32x4 v = *reinterpret_cast<const f32x4*>(&lds[e * STRIDE_DW + r * 4]);
            __builtin_nontemporal_store(v, &gout[j]);
        }
    }
}

extern "C" void kernel_launch(void* const* d_in, const int* in_sizes, int n_in,
                              void* d_out, int out_size, void* d_ws, size_t ws_size,
                              hipStream_t stream) {
    const float* x = (const float*)d_in[0];
    float* out = (float*)d_out;
    int n = in_sizes[0] / 48;   // events

    int grid = (n + EPB - 1) / EPB;   // N=2M -> 15625 blocks, no tail
    reorder_objects_kernel<<<grid, 256, 0, stream>>>(x, out, n);
}

// Round 4
// 127.300 us; speedup vs baseline: 1.9109x; 1.0369x over previous
//
#include <hip/hip_runtime.h>

// ReorderObjectsLayer: per-event stable stream-compaction of 4 particle groups.
// Input/Output: (N, 16, 3) float32. Groups: jets [0,6), electrons [6,9),
// muons [9,12), photons [12,15), met row 15 pass-through.
//
// LDS-staged, fully coalesced, nontemporal global access.
//   stage 1: 256 threads load 64 events (13.3 KB) lane-consecutive 16B loads
//   stage 2: event e split across 4 threads (wave-uniform):
//            wave0 jets dw[0,18) | wave1 electrons dw[18,27)
//            wave2 muons dw[27,36) | wave3 photons+met dw[36,48)
//   stage 3: lane-consecutive 16B stores
// LDS event stride 52 dwords: start bank group (52l)%32 covers all eight
// 4-bank groups every 8 lanes -> conflict-free b128 access.
// EPB=64 -> 13312 B LDS -> 8 blocks/CU x 4 waves = 32 waves/CU (100% occ).

#define EPB 64           // events per block
#define F4E 12           // 16B chunks per event
#define STRIDE_DW 52     // LDS dwords per event (48 + 4 pad)

typedef float f32x4 __attribute__((ext_vector_type(4)));

template<int S>
__device__ __forceinline__ void compact_rows(const float* in, float* o) {
    // S contiguous rows of 3 floats: stable-compact rows with col0>0, zero-pad.
    unsigned m = 0u;
#pragma unroll
    for (int s = 0; s < S; ++s)
        if (in[s * 3] > 0.0f) m |= (1u << s);
#pragma unroll
    for (int j = 0; j < S; ++j) {
        float a = 0.0f, b = 0.0f, c = 0.0f;
#pragma unroll
        for (int s = j; s < S; ++s) {   // j-th kept row can't be before index j
            bool take = (((m >> s) & 1u) != 0u) &&
                        (__popc(m & ((1u << s) - 1u)) == j);
            a = take ? in[s * 3 + 0] : a;
            b = take ? in[s * 3 + 1] : b;
            c = take ? in[s * 3 + 2] : c;
        }
        o[j * 3 + 0] = a;
        o[j * 3 + 1] = b;
        o[j * 3 + 2] = c;
    }
}

__global__ __launch_bounds__(256)
void reorder_objects_kernel(const float* __restrict__ x,
                            float* __restrict__ out, int n) {
    __shared__ float lds[EPB * STRIDE_DW];   // 13312 B

    const int t = threadIdx.x;
    const size_t ev0 = (size_t)blockIdx.x * EPB;
    int validEvents = n - (int)ev0;
    if (validEvents > EPB) validEvents = EPB;
    const bool full = (validEvents == EPB);

    // ---- stage 1: coalesced nontemporal global -> LDS ----
    const f32x4* __restrict__ gin =
        reinterpret_cast<const f32x4*>(x + ev0 * 48);
    if (full) {
#pragma unroll
        for (int k = 0; k < 3; ++k) {
            int j = t + k * 256;
            f32x4 v = __builtin_nontemporal_load(&gin[j]);
            int e = j / F4E;
            int r = j - e * F4E;
            *reinterpret_cast<f32x4*>(&lds[e * STRIDE_DW + r * 4]) = v;
        }
    } else {
        int validF4 = validEvents * F4E;
#pragma unroll
        for (int k = 0; k < 3; ++k) {
            int j = t + k * 256;
            if (j < validF4) {
                f32x4 v = __builtin_nontemporal_load(&gin[j]);
                int e = j / F4E;
                int r = j - e * F4E;
                *reinterpret_cast<f32x4*>(&lds[e * STRIDE_DW + r * 4]) = v;
            }
        }
    }
    __syncthreads();

    // ---- stage 2: per-event compaction, 4 threads/event, wave-uniform ----
    {
        const int w = t >> 6;       // wave id = group id
        const int l = t & 63;       // event id within block
        if (l < validEvents) {
            float* evb = &lds[l * STRIDE_DW];
            if (w == 0) {                       // jets: rows 0..5
                float in[18], o[18];
#pragma unroll
                for (int i = 0; i < 18; ++i) in[i] = evb[i];
                compact_rows<6>(in, o);
#pragma unroll
                for (int i = 0; i < 18; ++i) evb[i] = o[i];
            } else if (w == 1) {                // electrons: rows 6..8
                float in[9], o[9];
#pragma unroll
                for (int i = 0; i < 9; ++i) in[i] = evb[18 + i];
                compact_rows<3>(in, o);
#pragma unroll
                for (int i = 0; i < 9; ++i) evb[18 + i] = o[i];
            } else if (w == 2) {                // muons: rows 9..11
                float in[9], o[9];
#pragma unroll
                for (int i = 0; i < 9; ++i) in[i] = evb[27 + i];
                compact_rows<3>(in, o);
#pragma unroll
                for (int i = 0; i < 9; ++i) evb[27 + i] = o[i];
            } else {                            // photons rows 12..14 (+met)
                float in[9], o[9];
#pragma unroll
                for (int i = 0; i < 9; ++i) in[i] = evb[36 + i];
                compact_rows<3>(in, o);
#pragma unroll
                for (int i = 0; i < 9; ++i) evb[36 + i] = o[i];
                // met rows 45..47 pass through untouched in LDS
            }
        }
    }
    __syncthreads();

    // ---- stage 3: coalesced LDS -> nontemporal global ----
    f32x4* __restrict__ gout = reinterpret_cast<f32x4*>(out + ev0 * 48);
    if (full) {
#pragma unroll
        for (int k = 0; k < 3; ++k) {
            int j = t + k * 256;
            int e = j / F4E;
            int r = j - e * F4E;
            f32x4 v = *reinterpret_cast<const f32x4*>(&lds[e * STRIDE_DW + r * 4]);
            __builtin_nontemporal_store(v, &gout[j]);
        }
    } else {
        int validF4 = validEvents * F4E;
#pragma unroll
        for (int k = 0; k < 3; ++k) {
            int j = t + k * 256;
            if (j < validF4) {
                int e = j / F4E;
                int r = j - e * F4E;
                f32x4 v = *reinterpret_cast<const f32x4*>(&lds[e * STRIDE_DW + r * 4]);
                __builtin_nontemporal_store(v, &gout[j]);
            }
        }
    }
}

extern "C" void kernel_launch(void* const* d_in, const int* in_sizes, int n_in,
                              void* d_out, int out_size, void* d_ws, size_t ws_size,
                              hipStream_t stream) {
    const float* x = (const float*)d_in[0];
    float* out = (float*)d_out;
    int n = in_sizes[0] / 48;   // events

    int grid = (n + EPB - 1) / EPB;   // N=2M -> 31250 full blocks
    reorder_objects_kernel<<<grid, 256, 0, stream>>>(x, out, n);
}